// Round 10
// baseline (115.491 us; speedup 1.0000x reference)
//
#include <hip/hip_runtime.h>
#include <hip/hip_bf16.h>
#include <stdint.h>

#define XLEN   262144
#define NT     513
#define NTP    528               // padded frames per batch (8*528 = 4224 = 33*128)
#define NB     8
#define NCOL   (NB * NTP)        // 4224 fused columns
#define NKC    576               // padded computed k rows (valid: 0..512)
#define KH     1024              // half transform length (radix-2)
#define NFFT   2048
#define OUTKT  (2048 * NT)
#define NWG    297               // 9 * 33
#define EPITCH 132               // exchange row pitch (f32), pad 4 -> 2-way banks

typedef __attribute__((ext_vector_type(8))) short short8;
typedef __attribute__((ext_vector_type(4))) short short4v;
typedef __attribute__((ext_vector_type(4))) float f32x4;

__device__ __forceinline__ short cvt_bf16(float f) {
  return __builtin_bit_cast(short, (__bf16)f);
}

__device__ __forceinline__ void gload16(const short* g, const short* l) {
  __builtin_amdgcn_global_load_lds(
      (const __attribute__((address_space(1))) void*)g,
      (__attribute__((address_space(3))) void*)l, 16, 0, 0);
}

// ---- prep: split weights rows 0..512 by sample parity -> 4 bf16 mats [576][1024] ----
__global__ __launch_bounds__(256) void conv_w_split(
    const float* __restrict__ wsin, const float* __restrict__ wcos,
    short* __restrict__ wcE, short* __restrict__ wsE,
    short* __restrict__ wcO, short* __restrict__ wsO) {
  const int row = blockIdx.x;
  const int m0 = threadIdx.x * 4;
  short4v ce, se, co, so;
  if (row <= 512) {
    const float* pc = wcos + (size_t)row * NFFT + m0 * 2;
    const float* ps = wsin + (size_t)row * NFFT + m0 * 2;
    f32x4 c0 = *(const f32x4*)pc, c1 = *(const f32x4*)(pc + 4);
    f32x4 s0 = *(const f32x4*)ps, s1 = *(const f32x4*)(ps + 4);
    ce[0] = cvt_bf16(c0[0]); ce[1] = cvt_bf16(c0[2]); ce[2] = cvt_bf16(c1[0]); ce[3] = cvt_bf16(c1[2]);
    co[0] = cvt_bf16(c0[1]); co[1] = cvt_bf16(c0[3]); co[2] = cvt_bf16(c1[1]); co[3] = cvt_bf16(c1[3]);
    se[0] = cvt_bf16(s0[0]); se[1] = cvt_bf16(s0[2]); se[2] = cvt_bf16(s1[0]); se[3] = cvt_bf16(s1[2]);
    so[0] = cvt_bf16(s0[1]); so[1] = cvt_bf16(s0[3]); so[2] = cvt_bf16(s1[1]); so[3] = cvt_bf16(s1[3]);
  } else {
#pragma unroll
    for (int e = 0; e < 4; ++e) { ce[e] = 0; se[e] = 0; co[e] = 0; so[e] = 0; }
  }
  const size_t o = (size_t)row * KH + m0;
  *(short4v*)&wcE[o] = ce; *(short4v*)&wsE[o] = se;
  *(short4v*)&wcO[o] = co; *(short4v*)&wsO[o] = so;
}

// ---- prep: reflect-padded frames split by parity -> bf16 [4224][1024] x2 ----
__global__ __launch_bounds__(256) void conv_fr_split(const float* __restrict__ x,
                                                     short* __restrict__ frE,
                                                     short* __restrict__ frO) {
  const int j = blockIdx.x;
  const int b = j / NTP;
  const int t = j - b * NTP;
  const int m0 = threadIdx.x * 4;
  short4v ve, vo;
  if (t < NT) {
    const float* xb = x + (size_t)b * XLEN;
    const int q0 = t * 512 + 2 * m0 - 1024;
    float v[8];
    if (q0 >= 0 && q0 + 7 < XLEN) {
      *(f32x4*)(v)     = *(const f32x4*)(xb + q0);
      *(f32x4*)(v + 4) = *(const f32x4*)(xb + q0 + 4);
    } else {
#pragma unroll
      for (int e = 0; e < 8; ++e) {
        int mm = q0 + e;
        mm = (mm < 0) ? -mm : mm;
        mm = (mm >= XLEN) ? (2 * XLEN - 2 - mm) : mm;
        v[e] = xb[mm];
      }
    }
#pragma unroll
    for (int e = 0; e < 4; ++e) { ve[e] = cvt_bf16(v[2 * e]); vo[e] = cvt_bf16(v[2 * e + 1]); }
  } else {
#pragma unroll
    for (int e = 0; e < 4; ++e) { ve[e] = 0; vo[e] = 0; }
  }
  *(short4v*)&frE[(size_t)j * KH + m0] = ve;
  *(short4v*)&frO[(size_t)j * KH + m0] = vo;
}

// ---------------- main GEMM (radix-2, E/O wave-split, fused combine) ----------------
// 512 threads = 8 waves. Waves 0-3 (side 0): EC,ES over BM=64 x BN=128 tile
// (2x2 waves, each 32x64 per matrix, R4 geometry). Waves 4-7 (side 1): OC,OS.
// K=1024, BK=64 -> 16 K-steps, single 64 KiB buffer, 2 barriers/step.
// Per wave per substep: 8 ds_read_b128 : 16 MFMA (R4's proven ratio).
// Epilogue: LDS exchange (f32 [64][EPITCH] per side) combines E/O in-block;
// E writes rows k & 2048-k (k<=512), O writes rows 1024+k & 1024-k (k<=511).
template <bool WS>
__global__ __launch_bounds__(512, 4) void dft_gemm_kernel(
    const float* __restrict__ x,
    const float* __restrict__ wsin_f,
    const float* __restrict__ wcos_f,
    const short* __restrict__ wcE_g, const short* __restrict__ wsE_g,
    const short* __restrict__ wcO_g, const short* __restrict__ wsO_g,
    const short* __restrict__ frE_g, const short* __restrict__ frO_g,
    float* __restrict__ outR,
    float* __restrict__ outI) {
  __shared__ __align__(16) char smem[2 * 64 * EPITCH * 4];  // 67584 B >= 65536 staging
  short* lds = (short*)smem;

  const int tid  = threadIdx.x;
  const int lane = tid & 63;
  const int wid  = tid >> 6;        // 0..7
  const int side = wid >> 2;        // 0 = E, 1 = O
  const int w2   = wid & 3;

  // T1: bijective XCD swizzle (m204). nwg=297, q=37, r=1. k-major within XCD.
  const int o   = blockIdx.x;
  const int xcd = o & 7;
  const int wg  = ((xcd < 1) ? xcd * 38 : 38 + (xcd - 1) * 37) + (o >> 3);
  const int k0  = (wg % 9) * 64;
  const int j0  = (wg / 9) * 128;

  const int wrow = (w2 >> 1) * 32;  // k-offset of this wave
  const int wcol = (w2 & 1) * 64;   // j-offset of this wave

  f32x4 accC[2][4], accS[2][4];
#pragma unroll
  for (int m = 0; m < 2; ++m)
#pragma unroll
    for (int n = 0; n < 4; ++n) { accC[m][n] = (f32x4)0.0f; accS[m][n] = (f32x4)0.0f; }

  const int fr_r = lane & 15;        // fragment row
  const int srow = lane >> 3;        // 0..7 within an 8-row staging chunk
  const int scol = ((lane & 7) ^ srow) * 8;  // swizzled source 16B-chunk

  // buffer = 64 chunks of (8 rows x 64 shorts = 1 KiB); 8 per wave.
  // q: 0..7 wcE | 8..15 wsE | 16..23 wcO | 24..31 wsO | 32..47 frE | 48..63 frO
  auto stage = [&](int n0) {
#pragma unroll
    for (int i = 0; i < 8; ++i) {
      const int q = wid * 8 + i;  // wave-uniform
      if (WS) {
        const short* src;
        int dst;
        if (q < 8)       { src = wcE_g + (size_t)(k0 + (q & 7) * 8 + srow) * KH + n0 + scol; dst = (q & 7) * 512; }
        else if (q < 16) { src = wsE_g + (size_t)(k0 + (q & 7) * 8 + srow) * KH + n0 + scol; dst = 4096  + (q & 7) * 512; }
        else if (q < 24) { src = wcO_g + (size_t)(k0 + (q & 7) * 8 + srow) * KH + n0 + scol; dst = 8192  + (q & 7) * 512; }
        else if (q < 32) { src = wsO_g + (size_t)(k0 + (q & 7) * 8 + srow) * KH + n0 + scol; dst = 12288 + (q & 7) * 512; }
        else if (q < 48) { src = frE_g + (size_t)(j0 + (q & 15) * 8 + srow) * KH + n0 + scol; dst = 16384 + (q & 15) * 512; }
        else             { src = frO_g + (size_t)(j0 + (q & 15) * 8 + srow) * KH + n0 + scol; dst = 24576 + (q & 15) * 512; }
        gload16(src, &lds[dst]);
      } else {
        short8 v;
        int dst;
        if (q < 32) {
          const int mat = q >> 3;          // 0 cE, 1 sE, 2 cO, 3 sO
          const int par = mat >> 1;
          const int row = k0 + (q & 7) * 8 + srow;
          const float* wsrc = (mat & 1) ? wsin_f : wcos_f;
          if (row <= 512) {
#pragma unroll
            for (int e = 0; e < 8; ++e)
              v[e] = cvt_bf16(wsrc[(size_t)row * NFFT + 2 * (n0 + scol + e) + par]);
          } else {
#pragma unroll
            for (int e = 0; e < 8; ++e) v[e] = 0;
          }
          dst = mat * 4096 + (q & 7) * 512 + lane * 8;
        } else {
          const int par = (q >= 48);
          const int ch = q & 15;
          const int jj = j0 + ch * 8 + srow;
          const int b = jj / NTP, t = jj - b * NTP;
          if (t < NT) {
            const float* xb = x + (size_t)b * XLEN;
#pragma unroll
            for (int e = 0; e < 8; ++e) {
              int mm = t * 512 + 2 * (n0 + scol + e) + par - 1024;
              mm = (mm < 0) ? -mm : mm;
              mm = (mm >= XLEN) ? (2 * XLEN - 2 - mm) : mm;
              v[e] = cvt_bf16(xb[mm]);
            }
          } else {
#pragma unroll
            for (int e = 0; e < 8; ++e) v[e] = 0;
          }
          dst = (par ? 24576 : 16384) + ch * 512 + lane * 8;
        }
        *(short8*)&lds[dst] = v;
      }
    }
  };

  const int Abase = side * 8192;           // cE/cO
  const int Bbase = 16384 + side * 8192;   // frE/frO

  for (int ts = 0; ts < 16; ++ts) {
    if (ts) __syncthreads();
    stage(ts * 64);
    __syncthreads();
#pragma unroll
    for (int ks = 0; ks < 2; ++ks) {
      const int cc = ks * 4 + (lane >> 4);  // 16B-chunk within 64-short row
      short8 aC[2], aS[2], bF[4];
#pragma unroll
      for (int m = 0; m < 2; ++m) {
        const int r = wrow + m * 16 + fr_r;
        const int off = (r << 6) + ((cc ^ (r & 7)) << 3);
        aC[m] = *(const short8*)&lds[Abase + off];
        aS[m] = *(const short8*)&lds[Abase + 4096 + off];
      }
#pragma unroll
      for (int n = 0; n < 4; ++n) {
        const int r = wcol + n * 16 + fr_r;
        const int off = (r << 6) + ((cc ^ (r & 7)) << 3);
        bF[n] = *(const short8*)&lds[Bbase + off];
      }
#pragma unroll
      for (int m = 0; m < 2; ++m)
#pragma unroll
        for (int n = 0; n < 4; ++n) {
          accC[m][n] = __builtin_amdgcn_mfma_f32_16x16x32_bf16(aC[m], bF[n], accC[m][n], 0, 0, 0);
          accS[m][n] = __builtin_amdgcn_mfma_f32_16x16x32_bf16(aS[m], bF[n], accS[m][n], 0, 0, 0);
        }
    }
  }

  // ---- epilogue: in-block E/O combine via LDS exchange ----
  __syncthreads();  // last compute's ds_reads done; staging LDS reusable
  float* exch  = (float*)smem;
  float* mybuf = exch + side * (64 * EPITCH);
  float* obuf  = exch + (side ^ 1) * (64 * EPITCH);
  const int erow = wrow + (lane >> 4) * 4;          // + m*16 + r
  const int ecol = wcol + (lane & 15);              // + n*16

  // ---- round 1: C ----
#pragma unroll
  for (int m = 0; m < 2; ++m)
#pragma unroll
    for (int n = 0; n < 4; ++n)
#pragma unroll
      for (int r = 0; r < 4; ++r)
        mybuf[(erow + m * 16 + r) * EPITCH + ecol + n * 16] = accC[m][n][r];
  __syncthreads();
#pragma unroll
  for (int m = 0; m < 2; ++m) {
    const int kb = k0 + erow + m * 16;
#pragma unroll
    for (int n = 0; n < 4; ++n) {
      const int j = j0 + ecol + n * 16;
      const int b = j / NTP;
      const int t = j - b * NTP;
      if (t < NT) {
        const size_t bb = (size_t)b * OUTKT + t;
#pragma unroll
        for (int r = 0; r < 4; ++r) {
          const int k = kb + r;
          const float other = obuf[(erow + m * 16 + r) * EPITCH + ecol + n * 16];
          const float mine  = accC[m][n][r];
          if (side == 0) {            // mine=EC, other=OC
            if (k <= 512) {
              const float c1 = mine + other;
              outR[bb + (size_t)k * NT] = c1;
              if (k >= 1) outR[bb + (size_t)(2048 - k) * NT] = c1;
            }
          } else {                    // mine=OC, other=EC
            if (k <= 511) {
              const float c2 = other - mine;
              outR[bb + (size_t)(1024 + k) * NT] = c2;
              outR[bb + (size_t)(1024 - k) * NT] = c2;
            }
          }
        }
      }
    }
  }
  __syncthreads();

  // ---- round 2: S ----
#pragma unroll
  for (int m = 0; m < 2; ++m)
#pragma unroll
    for (int n = 0; n < 4; ++n)
#pragma unroll
      for (int r = 0; r < 4; ++r)
        mybuf[(erow + m * 16 + r) * EPITCH + ecol + n * 16] = accS[m][n][r];
  __syncthreads();
#pragma unroll
  for (int m = 0; m < 2; ++m) {
    const int kb = k0 + erow + m * 16;
#pragma unroll
    for (int n = 0; n < 4; ++n) {
      const int j = j0 + ecol + n * 16;
      const int b = j / NTP;
      const int t = j - b * NTP;
      if (t < NT) {
        const size_t bb = (size_t)b * OUTKT + t;
#pragma unroll
        for (int r = 0; r < 4; ++r) {
          const int k = kb + r;
          const float other = obuf[(erow + m * 16 + r) * EPITCH + ecol + n * 16];
          const float mine  = accS[m][n][r];
          if (side == 0) {            // mine=ES, other=OS
            if (k <= 512) {
              const float s1 = mine + other;
              outI[bb + (size_t)k * NT] = -s1;
              if (k >= 1) outI[bb + (size_t)(2048 - k) * NT] = s1;
            }
          } else {                    // mine=OS, other=ES
            if (k <= 511) {
              const float s2 = other - mine;
              outI[bb + (size_t)(1024 + k) * NT] = -s2;
              outI[bb + (size_t)(1024 - k) * NT] = s2;
            }
          }
        }
      }
    }
  }
}

extern "C" void kernel_launch(void* const* d_in, const int* in_sizes, int n_in,
                              void* d_out, int out_size, void* d_ws, size_t ws_size,
                              hipStream_t stream) {
  const float* x    = (const float*)d_in[0];
  const float* wsin = (const float*)d_in[1];
  const float* wcos = (const float*)d_in[2];
  float* outR = (float*)d_out;
  float* outI = outR + (size_t)NB * OUTKT;

  short* wcE = (short*)d_ws;
  short* wsE = wcE + (size_t)NKC * KH;
  short* wcO = wsE + (size_t)NKC * KH;
  short* wsO = wcO + (size_t)NKC * KH;
  short* frE = wsO + (size_t)NKC * KH;
  short* frO = frE + (size_t)NCOL * KH;
  const size_t ws_need = ((size_t)4 * NKC + 2 * NCOL) * KH * sizeof(short);  // ~22 MB

  if (ws_size >= ws_need) {
    conv_w_split<<<NKC, 256, 0, stream>>>(wsin, wcos, wcE, wsE, wcO, wsO);
    conv_fr_split<<<NCOL, 256, 0, stream>>>(x, frE, frO);
    dft_gemm_kernel<true><<<NWG, 512, 0, stream>>>(x, wsin, wcos, wcE, wsE, wcO, wsO, frE, frO, outR, outI);
  } else {
    dft_gemm_kernel<false><<<NWG, 512, 0, stream>>>(x, wsin, wcos, wcE, wsE, wcO, wsO, frE, frO, outR, outI);
  }
}

// Round 11
// 75.852 us; speedup vs baseline: 1.5226x; 1.5226x over previous
//
#include <hip/hip_runtime.h>
#include <hip/hip_bf16.h>
#include <stdint.h>

#define XLEN   262144
#define NT     513
#define NTP    528               // padded frames per batch (8*528 = 4224)
#define NB     8
#define NCOL   (NB * NTP)        // 4224 fused columns
#define NKC    576               // padded computed k rows (valid 0..512)
#define KH     1024              // half transform length (radix-2)
#define NK     1088              // fallback path: direct rows
#define NFFT   2048
#define OUTKT  (2048 * NT)

typedef __attribute__((ext_vector_type(8))) short short8;
typedef __attribute__((ext_vector_type(4))) short short4v;
typedef __attribute__((ext_vector_type(4))) float f32x4;

__device__ __forceinline__ short cvt_bf16(float f) {
  return __builtin_bit_cast(short, (__bf16)f);
}

__device__ __forceinline__ void gload16(const short* g, const short* l) {
  __builtin_amdgcn_global_load_lds(
      (const __attribute__((address_space(1))) void*)g,
      (__attribute__((address_space(3))) void*)l, 16, 0, 0);
}

// ==================== radix-2 split path ====================

// ---- prep: split weights rows 0..512 by sample parity -> 4 bf16 mats [576][1024] ----
__global__ __launch_bounds__(256) void conv_w_split(
    const float* __restrict__ wsin, const float* __restrict__ wcos,
    short* __restrict__ wcE, short* __restrict__ wsE,
    short* __restrict__ wcO, short* __restrict__ wsO) {
  const int row = blockIdx.x;
  const int m0 = threadIdx.x * 4;
  short4v ce, se, co, so;
  if (row <= 512) {
    const float* pc = wcos + (size_t)row * NFFT + m0 * 2;
    const float* ps = wsin + (size_t)row * NFFT + m0 * 2;
    f32x4 c0 = *(const f32x4*)pc, c1 = *(const f32x4*)(pc + 4);
    f32x4 s0 = *(const f32x4*)ps, s1 = *(const f32x4*)(ps + 4);
    ce[0] = cvt_bf16(c0[0]); ce[1] = cvt_bf16(c0[2]); ce[2] = cvt_bf16(c1[0]); ce[3] = cvt_bf16(c1[2]);
    co[0] = cvt_bf16(c0[1]); co[1] = cvt_bf16(c0[3]); co[2] = cvt_bf16(c1[1]); co[3] = cvt_bf16(c1[3]);
    se[0] = cvt_bf16(s0[0]); se[1] = cvt_bf16(s0[2]); se[2] = cvt_bf16(s1[0]); se[3] = cvt_bf16(s1[2]);
    so[0] = cvt_bf16(s0[1]); so[1] = cvt_bf16(s0[3]); so[2] = cvt_bf16(s1[1]); so[3] = cvt_bf16(s1[3]);
  } else {
#pragma unroll
    for (int e = 0; e < 4; ++e) { ce[e] = 0; se[e] = 0; co[e] = 0; so[e] = 0; }
  }
  const size_t o = (size_t)row * KH + m0;
  *(short4v*)&wcE[o] = ce; *(short4v*)&wsE[o] = se;
  *(short4v*)&wcO[o] = co; *(short4v*)&wsO[o] = so;
}

// ---- prep: reflect-padded frames split by parity -> bf16 [4224][1024] x2 ----
__global__ __launch_bounds__(256) void conv_fr_split(const float* __restrict__ x,
                                                     short* __restrict__ frE,
                                                     short* __restrict__ frO) {
  const int j = blockIdx.x;
  const int b = j / NTP;
  const int t = j - b * NTP;
  const int m0 = threadIdx.x * 4;
  short4v ve, vo;
  if (t < NT) {
    const float* xb = x + (size_t)b * XLEN;
    const int q0 = t * 512 + 2 * m0 - 1024;
    float v[8];
    if (q0 >= 0 && q0 + 7 < XLEN) {
      *(f32x4*)(v)     = *(const f32x4*)(xb + q0);
      *(f32x4*)(v + 4) = *(const f32x4*)(xb + q0 + 4);
    } else {
#pragma unroll
      for (int e = 0; e < 8; ++e) {
        int mm = q0 + e;
        mm = (mm < 0) ? -mm : mm;
        mm = (mm >= XLEN) ? (2 * XLEN - 2 - mm) : mm;
        v[e] = xb[mm];
      }
    }
#pragma unroll
    for (int e = 0; e < 4; ++e) { ve[e] = cvt_bf16(v[2 * e]); vo[e] = cvt_bf16(v[2 * e + 1]); }
  } else {
#pragma unroll
    for (int e = 0; e < 4; ++e) { ve[e] = 0; vo[e] = 0; }
  }
  *(short4v*)&frE[(size_t)j * KH + m0] = ve;
  *(short4v*)&frO[(size_t)j * KH + m0] = vo;
}

// ---- split GEMM: R4-proven structure, K=1024, one side (E or O) per block ----
// BM=64, BN=128, BK=64; 4 waves 2x2, each 32x64 per matrix; per substep
// 8 ds_read_b128 : 16 MFMA. LDS single 32 KiB [A_c 64x64 | A_s 64x64 | B 128x64],
// (row&7) 16B-chunk XOR swizzle on global source + ds_read (rule #21).
// Writes linear fp32 partials [576][4224], fully coalesced.
__global__ __launch_bounds__(256, 3) void dft_gemm_split(
    const short* __restrict__ wcE, const short* __restrict__ wsE,
    const short* __restrict__ wcO, const short* __restrict__ wsO,
    const short* __restrict__ frE, const short* __restrict__ frO,
    float* __restrict__ pEC, float* __restrict__ pES,
    float* __restrict__ pOC, float* __restrict__ pOS) {
  __shared__ short lds[16384];  // 32 KiB

  const int tid  = threadIdx.x;
  const int lane = tid & 63;
  const int wid  = tid >> 6;

  // bijective XCD swizzle (m204): nwg=594, q=74, r=2. k-major within XCD
  // (consecutive wg share a j-tile); sides split across XCD halves.
  const int o   = blockIdx.x;
  const int xcd = o & 7;
  const int wg  = ((xcd < 2) ? xcd * 75 : 150 + (xcd - 2) * 74) + (o >> 3);
  const int side = wg / 297;        // 0 = E, 1 = O
  const int w    = wg - side * 297;
  const int k0   = (w % 9) * 64;
  const int j0   = (w / 9) * 128;

  const short* Ac = side ? wcO : wcE;
  const short* As = side ? wsO : wsE;
  const short* Bf = side ? frO : frE;
  float* pC = side ? pOC : pEC;
  float* pS = side ? pOS : pES;

  const int wrow = (wid >> 1) * 32;
  const int wcol = (wid & 1) * 64;

  f32x4 accC[2][4], accS[2][4];
#pragma unroll
  for (int m = 0; m < 2; ++m)
#pragma unroll
    for (int n = 0; n < 4; ++n) { accC[m][n] = (f32x4)0.0f; accS[m][n] = (f32x4)0.0f; }

  const int fr_r = lane & 15;
  const int srow = lane >> 3;
  const int scol = ((lane & 7) ^ srow) * 8;

  // buffer = 32 chunks of (8 rows x 64 shorts); 8 per wave
  auto stage = [&](int n0) {
#pragma unroll
    for (int i = 0; i < 8; ++i) {
      const int q = wid * 8 + i;  // wave-uniform
      const short* src;
      int dst;
      if (q < 8) {
        src = Ac + (size_t)(k0 + q * 8 + srow) * KH + n0 + scol;
        dst = q * 512;
      } else if (q < 16) {
        src = As + (size_t)(k0 + (q - 8) * 8 + srow) * KH + n0 + scol;
        dst = 4096 + (q - 8) * 512;
      } else {
        src = Bf + (size_t)(j0 + (q - 16) * 8 + srow) * KH + n0 + scol;
        dst = 8192 + (q - 16) * 512;
      }
      gload16(src, &lds[dst]);
    }
  };

  for (int ts = 0; ts < 16; ++ts) {
    if (ts) __syncthreads();
    stage(ts * 64);
    __syncthreads();
#pragma unroll
    for (int ks = 0; ks < 2; ++ks) {
      const int cc = ks * 4 + (lane >> 4);
      short8 aC[2], aS[2], bF[4];
#pragma unroll
      for (int m = 0; m < 2; ++m) {
        const int r = wrow + m * 16 + fr_r;
        const int off = (r << 6) + ((cc ^ (r & 7)) << 3);
        aC[m] = *(const short8*)&lds[off];
        aS[m] = *(const short8*)&lds[4096 + off];
      }
#pragma unroll
      for (int n = 0; n < 4; ++n) {
        const int r = wcol + n * 16 + fr_r;
        const int off = (r << 6) + ((cc ^ (r & 7)) << 3);
        bF[n] = *(const short8*)&lds[8192 + off];
      }
#pragma unroll
      for (int m = 0; m < 2; ++m)
#pragma unroll
        for (int n = 0; n < 4; ++n) {
          accC[m][n] = __builtin_amdgcn_mfma_f32_16x16x32_bf16(aC[m], bF[n], accC[m][n], 0, 0, 0);
          accS[m][n] = __builtin_amdgcn_mfma_f32_16x16x32_bf16(aS[m], bF[n], accS[m][n], 0, 0, 0);
        }
    }
  }

  // epilogue: linear coalesced partial write
#pragma unroll
  for (int m = 0; m < 2; ++m) {
    const int row = k0 + wrow + m * 16 + (lane >> 4) * 4;
#pragma unroll
    for (int n = 0; n < 4; ++n) {
      const int col = j0 + wcol + n * 16 + (lane & 15);
      const size_t base = (size_t)row * NCOL + col;
#pragma unroll
      for (int r = 0; r < 4; ++r) {
        pC[base + (size_t)r * NCOL] = accC[m][n][r];
        pS[base + (size_t)r * NCOL] = accS[m][n][r];
      }
    }
  }
}

// ---- combine: X_k = E + O', X_{k+1024} = E - O', Hermitian mirrors ----
// Row ownership (verified R10, disjoint): c1 -> rows k (k<=512) and 2048-k
// (1<=k<=512); c2 -> rows 1024+k (k<=511) and 1024-k (1<=k<=511).
__global__ __launch_bounds__(256) void combine_kernel(
    const float* __restrict__ pEC, const float* __restrict__ pES,
    const float* __restrict__ pOC, const float* __restrict__ pOS,
    float* __restrict__ outR, float* __restrict__ outI) {
  const int k  = blockIdx.y;                       // 0..512
  const int jq = blockIdx.x * 256 + threadIdx.x;   // 0..1055 (guard)
  if (jq >= NCOL / 4) return;
  const int j = jq * 4;
  const int b = j / NTP;
  const int t = j - b * NTP;                       // NTP%4==0 -> same b for all 4
  const size_t pb = (size_t)k * NCOL + j;
  const f32x4 EC = *(const f32x4*)&pEC[pb];
  const f32x4 OC = *(const f32x4*)&pOC[pb];
  const f32x4 ES = *(const f32x4*)&pES[pb];
  const f32x4 OS = *(const f32x4*)&pOS[pb];
  const f32x4 c1 = EC + OC, s1 = ES + OS;
  const f32x4 c2 = EC - OC, s2 = ES - OS;
  const size_t ob = (size_t)b * OUTKT + t;

  float* r1  = outR + ob + (size_t)k * NT;
  float* i1  = outI + ob + (size_t)k * NT;
  float* r1m = outR + ob + (size_t)(2048 - k) * NT;
  float* i1m = outI + ob + (size_t)(2048 - k) * NT;
  float* r2  = outR + ob + (size_t)(1024 + k) * NT;
  float* i2  = outI + ob + (size_t)(1024 + k) * NT;
  float* r2m = outR + ob + (size_t)(1024 - k) * NT;
  float* i2m = outI + ob + (size_t)(1024 - k) * NT;

#pragma unroll
  for (int e = 0; e < 4; ++e) {
    if (t + e < NT) {
      r1[e] = c1[e];
      i1[e] = -s1[e];
      if (k >= 1) { r1m[e] = c1[e]; i1m[e] = s1[e]; }
      if (k <= 511) {
        r2[e] = c2[e];
        i2[e] = -s2[e];
        if (k >= 1) { r2m[e] = c2[e]; i2m[e] = s2[e]; }
      }
    }
  }
}

// ==================== fallback: R4 full-K path (proven, 77.8 us) ====================

__global__ __launch_bounds__(256) void conv_w_kernel(const float* __restrict__ wsin,
                                                     const float* __restrict__ wcos,
                                                     short* __restrict__ wc,
                                                     short* __restrict__ ws) {
  const int row = blockIdx.x;
  const int c = threadIdx.x * 8;
  const float* src = (blockIdx.y ? wsin : wcos) + (size_t)row * NFFT + c;
  short* dst = (blockIdx.y ? ws : wc) + (size_t)row * NFFT + c;
  f32x4 a = *(const f32x4*)src;
  f32x4 b = *(const f32x4*)(src + 4);
  short8 o;
#pragma unroll
  for (int j = 0; j < 4; ++j) { o[j] = cvt_bf16(a[j]); o[4 + j] = cvt_bf16(b[j]); }
  *(short8*)dst = o;
}

__global__ __launch_bounds__(256) void conv_frames_kernel(const float* __restrict__ x,
                                                          short* __restrict__ fr) {
  const int j = blockIdx.x;
  const int b = j / NTP;
  const int t = j - b * NTP;
  const int c = threadIdx.x * 8;
  short8 o;
  if (t >= NT) {
#pragma unroll
    for (int k = 0; k < 8; ++k) o[k] = 0;
  } else {
    const float* xb = x + (size_t)b * XLEN;
    const int base = t * 512 + c - 1024;
    float v[8];
    if (base >= 0 && base + 7 < XLEN) {
      *(f32x4*)(v)     = *(const f32x4*)(xb + base);
      *(f32x4*)(v + 4) = *(const f32x4*)(xb + base + 4);
    } else {
#pragma unroll
      for (int k = 0; k < 8; ++k) {
        int m = base + k;
        m = (m < 0) ? -m : m;
        m = (m >= XLEN) ? (2 * XLEN - 2 - m) : m;
        v[k] = xb[m];
      }
    }
#pragma unroll
    for (int k = 0; k < 8; ++k) o[k] = cvt_bf16(v[k]);
  }
  *(short8*)&fr[(size_t)j * NFFT + c] = o;
}

__global__ __launch_bounds__(256, 3) void dft_gemm_r4(
    const short* __restrict__ wc_bf,
    const short* __restrict__ ws_bf,
    const short* __restrict__ fr_bf,
    float* __restrict__ outR,
    float* __restrict__ outI) {
  __shared__ short lds[16384];

  const int tid  = threadIdx.x;
  const int lane = tid & 63;
  const int wid  = tid >> 6;

  const int o   = blockIdx.x;
  const int xcd = o & 7;
  const int wg  = ((xcd < 1) ? xcd * 71 : 71 + (xcd - 1) * 70) + (o >> 3);
  const int k0  = (wg % 17) * 64;
  const int j0  = (wg / 17) * 128;

  const int wrow = (wid >> 1) * 32;
  const int wcol = (wid & 1) * 64;

  f32x4 accR[2][4], accI[2][4];
#pragma unroll
  for (int m = 0; m < 2; ++m)
#pragma unroll
    for (int n = 0; n < 4; ++n) { accR[m][n] = (f32x4)0.0f; accI[m][n] = (f32x4)0.0f; }

  const int fr_r = lane & 15;
  const int srow = lane >> 3;
  const int scol = ((lane & 7) ^ srow) * 8;

  auto stage = [&](int n0) {
#pragma unroll
    for (int i = 0; i < 8; ++i) {
      const int q = wid * 8 + i;
      const short* src;
      int dst;
      if (q < 8) {
        src = wc_bf + (size_t)(k0 + q * 8 + srow) * NFFT + n0 + scol;
        dst = q * 512;
      } else if (q < 16) {
        src = ws_bf + (size_t)(k0 + (q - 8) * 8 + srow) * NFFT + n0 + scol;
        dst = 4096 + (q - 8) * 512;
      } else {
        src = fr_bf + (size_t)(j0 + (q - 16) * 8 + srow) * NFFT + n0 + scol;
        dst = 8192 + (q - 16) * 512;
      }
      gload16(src, &lds[dst]);
    }
  };

  for (int t = 0; t < 32; ++t) {
    if (t) __syncthreads();
    stage(t * 64);
    __syncthreads();
#pragma unroll
    for (int ks = 0; ks < 2; ++ks) {
      const int cc = ks * 4 + (lane >> 4);
      short8 a_c[2], a_s[2], b_f[4];
#pragma unroll
      for (int m = 0; m < 2; ++m) {
        const int r = wrow + m * 16 + fr_r;
        const int off = (r << 6) + ((cc ^ (r & 7)) << 3);
        a_c[m] = *(const short8*)&lds[off];
        a_s[m] = *(const short8*)&lds[4096 + off];
      }
#pragma unroll
      for (int n = 0; n < 4; ++n) {
        const int r = wcol + n * 16 + fr_r;
        const int off = (r << 6) + ((cc ^ (r & 7)) << 3);
        b_f[n] = *(const short8*)&lds[8192 + off];
      }
#pragma unroll
      for (int m = 0; m < 2; ++m)
#pragma unroll
        for (int n = 0; n < 4; ++n) {
          accR[m][n] = __builtin_amdgcn_mfma_f32_16x16x32_bf16(a_c[m], b_f[n], accR[m][n], 0, 0, 0);
          accI[m][n] = __builtin_amdgcn_mfma_f32_16x16x32_bf16(a_s[m], b_f[n], accI[m][n], 0, 0, 0);
        }
    }
  }

#pragma unroll
  for (int m = 0; m < 2; ++m) {
    const int k = k0 + wrow + m * 16 + (lane >> 4) * 4;
#pragma unroll
    for (int n = 0; n < 4; ++n) {
      const int j = j0 + wcol + n * 16 + (lane & 15);
      const int b = j / NTP;
      const int t = j - b * NTP;
      if (t < NT) {
        const size_t base = (size_t)b * OUTKT + (size_t)k * NT + t;
#pragma unroll
        for (int r = 0; r < 4; ++r) {
          const int kk = k + r;
          const float vr = accR[m][n][r];
          const float vi = accI[m][n][r];
          outR[base + (size_t)r * NT] = vr;
          outI[base + (size_t)r * NT] = -vi;
          if (kk >= 1 && kk <= 960) {
            const size_t mb = (size_t)b * OUTKT + (size_t)(2048 - kk) * NT + t;
            outR[mb] = vr;
            outI[mb] = vi;
          }
        }
      }
    }
  }
}

// ==================== host ====================

extern "C" void kernel_launch(void* const* d_in, const int* in_sizes, int n_in,
                              void* d_out, int out_size, void* d_ws, size_t ws_size,
                              hipStream_t stream) {
  const float* x    = (const float*)d_in[0];
  const float* wsin = (const float*)d_in[1];
  const float* wcos = (const float*)d_in[2];
  float* outR = (float*)d_out;
  float* outI = outR + (size_t)NB * OUTKT;

  // split-path workspace: 4 weight mats + 2 frame mats (bf16) + 4 fp32 partials
  const size_t wsz  = (size_t)NKC * KH;          // 589,824 shorts per weight mat
  const size_t fsz  = (size_t)NCOL * KH;         // 4,325,376 shorts per frame mat
  const size_t psz  = (size_t)NKC * NCOL;        // 2,433,024 floats per partial
  const size_t need_split = (4 * wsz + 2 * fsz) * sizeof(short) + 4 * psz * sizeof(float);

  if (ws_size >= need_split) {
    short* wcE = (short*)d_ws;
    short* wsE = wcE + wsz;
    short* wcO = wsE + wsz;
    short* wsO = wcO + wsz;
    short* frE = wsO + wsz;
    short* frO = frE + fsz;
    float* pEC = (float*)(frO + fsz);
    float* pES = pEC + psz;
    float* pOC = pES + psz;
    float* pOS = pOC + psz;

    conv_w_split<<<NKC, 256, 0, stream>>>(wsin, wcos, wcE, wsE, wcO, wsO);
    conv_fr_split<<<NCOL, 256, 0, stream>>>(x, frE, frO);
    dft_gemm_split<<<594, 256, 0, stream>>>(wcE, wsE, wcO, wsO, frE, frO,
                                            pEC, pES, pOC, pOS);
    combine_kernel<<<dim3(5, 513), 256, 0, stream>>>(pEC, pES, pOC, pOS, outR, outI);
  } else {
    // R4 full-K fallback (needs ~26.2 MB, proven available)
    short* wc_bf = (short*)d_ws;
    short* ws_bf = wc_bf + (size_t)NK * NFFT;
    short* fr_bf = ws_bf + (size_t)NK * NFFT;
    conv_w_kernel<<<dim3(NK, 2), 256, 0, stream>>>(wsin, wcos, wc_bf, ws_bf);
    conv_frames_kernel<<<NCOL, 256, 0, stream>>>(x, fr_bf);
    dft_gemm_r4<<<561, 256, 0, stream>>>(wc_bf, ws_bf, fr_bf, outR, outI);
  }
}

// Round 13
// 65.909 us; speedup vs baseline: 1.7523x; 1.1509x over previous
//
#include <hip/hip_runtime.h>
#include <hip/hip_bf16.h>
#include <stdint.h>

#define XLEN   262144
#define NT     513
#define NTP    528               // padded frames per batch (8*528 = 4224)
#define NB     8
#define NCOL   (NB * NTP)        // 4224 fused columns
#define NKC4   320               // padded computed k rows (valid 0..256), 5 tiles
#define KQ     512               // quarter transform length (radix-4)
#define NK     1088              // fallback path: direct rows
#define NFFT   2048
#define OUTKT  (2048 * NT)
#define WSTR   ((size_t)NKC4 * KQ)   // 163,840 shorts per weight mat
#define FSTR   ((size_t)NCOL * KQ)   // 2,162,688 shorts per frame mat
#define PSTR   ((size_t)NKC4 * NCOL) // 1,351,680 floats per partial

typedef __attribute__((ext_vector_type(8))) short short8;
typedef __attribute__((ext_vector_type(2))) short short2v;
typedef __attribute__((ext_vector_type(4))) float f32x4;

__device__ __forceinline__ short cvt_bf16(float f) {
  return __builtin_bit_cast(short, (__bf16)f);
}

__device__ __forceinline__ void gload16(const short* g, const short* l) {
  __builtin_amdgcn_global_load_lds(
      (const __attribute__((address_space(1))) void*)g,
      (__attribute__((address_space(3))) void*)l, 16, 0, 0);
}

// ==================== radix-4 split path ====================

// ---- prep: weights rows 0..256 split by n mod 4 -> 8 bf16 mats [320][512] ----
__global__ __launch_bounds__(256) void conv_w_split4(
    const float* __restrict__ wsin, const float* __restrict__ wcos,
    short* __restrict__ wc4, short* __restrict__ ws4) {
  const int row = blockIdx.x;           // 0..319
  const int n0 = threadIdx.x * 8;       // 8 consecutive n; m0 = n0/4 (even)
  const int m0 = n0 >> 2;
  short2v c[4], s[4];
  if (row <= 256) {
    const float* pc = wcos + (size_t)row * NFFT + n0;
    const float* ps = wsin + (size_t)row * NFFT + n0;
    f32x4 c0 = *(const f32x4*)pc, c1 = *(const f32x4*)(pc + 4);
    f32x4 s0 = *(const f32x4*)ps, s1 = *(const f32x4*)(ps + 4);
#pragma unroll
    for (int r = 0; r < 4; ++r) {
      c[r][0] = cvt_bf16(c0[r]); c[r][1] = cvt_bf16(c1[r]);
      s[r][0] = cvt_bf16(s0[r]); s[r][1] = cvt_bf16(s1[r]);
    }
  } else {
#pragma unroll
    for (int r = 0; r < 4; ++r) { c[r][0] = 0; c[r][1] = 0; s[r][0] = 0; s[r][1] = 0; }
  }
#pragma unroll
  for (int r = 0; r < 4; ++r) {
    *(short2v*)&wc4[r * WSTR + (size_t)row * KQ + m0] = c[r];
    *(short2v*)&ws4[r * WSTR + (size_t)row * KQ + m0] = s[r];
  }
}

// ---- prep: reflect-padded frames split by n mod 4 -> 4 bf16 mats [4224][512] ----
__global__ __launch_bounds__(256) void conv_fr_split4(const float* __restrict__ x,
                                                      short* __restrict__ fr4) {
  const int j = blockIdx.x;
  const int b = j / NTP;
  const int t = j - b * NTP;
  const int n0 = threadIdx.x * 8;
  const int m0 = n0 >> 2;
  short2v v[4];
  if (t < NT) {
    const float* xb = x + (size_t)b * XLEN;
    const int q0 = t * 512 + n0 - 1024;
    float f[8];
    if (q0 >= 0 && q0 + 7 < XLEN) {
      *(f32x4*)(f)     = *(const f32x4*)(xb + q0);
      *(f32x4*)(f + 4) = *(const f32x4*)(xb + q0 + 4);
    } else {
#pragma unroll
      for (int e = 0; e < 8; ++e) {
        int mm = q0 + e;
        mm = (mm < 0) ? -mm : mm;
        mm = (mm >= XLEN) ? (2 * XLEN - 2 - mm) : mm;
        f[e] = xb[mm];
      }
    }
#pragma unroll
    for (int r = 0; r < 4; ++r) { v[r][0] = cvt_bf16(f[r]); v[r][1] = cvt_bf16(f[4 + r]); }
  } else {
#pragma unroll
    for (int r = 0; r < 4; ++r) { v[r][0] = 0; v[r][1] = 0; }
  }
#pragma unroll
  for (int r = 0; r < 4; ++r)
    *(short2v*)&fr4[r * FSTR + (size_t)j * KQ + m0] = v[r];
}

// ---- split GEMM: R11-proven structure, K=512, one residue side per block ----
// BM=64, BN=128, BK=64; 4 waves 2x2, each 32x64 per matrix; per substep
// 8 ds_read_b128 : 16 MFMA. LDS single 32 KiB [A_c 64x64 | A_s 64x64 | B 128x64],
// (row&7) 16B-chunk XOR swizzle on global source + ds_read (rule #21).
__global__ __launch_bounds__(256, 3) void dft_gemm_split4(
    const short* __restrict__ wc4, const short* __restrict__ ws4,
    const short* __restrict__ fr4,
    float* __restrict__ pC4, float* __restrict__ pS4) {
  __shared__ short lds[16384];  // 32 KiB

  const int tid  = threadIdx.x;
  const int lane = tid & 63;
  const int wid  = tid >> 6;

  // bijective XCD swizzle (m204): nwg=660, q=82, r=4.
  const int o   = blockIdx.x;
  const int xcd = o & 7;
  const int i   = o >> 3;
  const int wg  = ((xcd < 4) ? xcd * 83 : 332 + (xcd - 4) * 82) + i;
  const int side = wg / 165;        // residue r = 0..3
  const int w    = wg - side * 165;
  const int k0   = (w % 5) * 64;
  const int j0   = (w / 5) * 128;

  const short* Ac = wc4 + side * WSTR;
  const short* As = ws4 + side * WSTR;
  const short* Bf = fr4 + side * FSTR;
  float* pC = pC4 + side * PSTR;
  float* pS = pS4 + side * PSTR;

  const int wrow = (wid >> 1) * 32;
  const int wcol = (wid & 1) * 64;

  f32x4 accC[2][4], accS[2][4];
#pragma unroll
  for (int m = 0; m < 2; ++m)
#pragma unroll
    for (int n = 0; n < 4; ++n) { accC[m][n] = (f32x4)0.0f; accS[m][n] = (f32x4)0.0f; }

  const int fr_r = lane & 15;
  const int srow = lane >> 3;
  const int scol = ((lane & 7) ^ srow) * 8;

  // buffer = 32 chunks of (8 rows x 64 shorts); 8 per wave
  auto stage = [&](int n0) {
#pragma unroll
    for (int i2 = 0; i2 < 8; ++i2) {
      const int q = wid * 8 + i2;  // wave-uniform
      const short* src;
      int dst;
      if (q < 8) {
        src = Ac + (size_t)(k0 + q * 8 + srow) * KQ + n0 + scol;
        dst = q * 512;
      } else if (q < 16) {
        src = As + (size_t)(k0 + (q - 8) * 8 + srow) * KQ + n0 + scol;
        dst = 4096 + (q - 8) * 512;
      } else {
        src = Bf + (size_t)(j0 + (q - 16) * 8 + srow) * KQ + n0 + scol;
        dst = 8192 + (q - 16) * 512;
      }
      gload16(src, &lds[dst]);
    }
  };

  for (int ts = 0; ts < 8; ++ts) {
    if (ts) __syncthreads();
    stage(ts * 64);
    __syncthreads();
#pragma unroll
    for (int ks = 0; ks < 2; ++ks) {
      const int cc = ks * 4 + (lane >> 4);
      short8 aC[2], aS[2], bF[4];
#pragma unroll
      for (int m = 0; m < 2; ++m) {
        const int r = wrow + m * 16 + fr_r;
        const int off = (r << 6) + ((cc ^ (r & 7)) << 3);
        aC[m] = *(const short8*)&lds[off];
        aS[m] = *(const short8*)&lds[4096 + off];
      }
#pragma unroll
      for (int n = 0; n < 4; ++n) {
        const int r = wcol + n * 16 + fr_r;
        const int off = (r << 6) + ((cc ^ (r & 7)) << 3);
        bF[n] = *(const short8*)&lds[8192 + off];
      }
#pragma unroll
      for (int m = 0; m < 2; ++m)
#pragma unroll
        for (int n = 0; n < 4; ++n) {
          accC[m][n] = __builtin_amdgcn_mfma_f32_16x16x32_bf16(aC[m], bF[n], accC[m][n], 0, 0, 0);
          accS[m][n] = __builtin_amdgcn_mfma_f32_16x16x32_bf16(aS[m], bF[n], accS[m][n], 0, 0, 0);
        }
    }
  }

  // epilogue: linear coalesced partial write
#pragma unroll
  for (int m = 0; m < 2; ++m) {
    const int row = k0 + wrow + m * 16 + (lane >> 4) * 4;
#pragma unroll
    for (int n = 0; n < 4; ++n) {
      const int col = j0 + wcol + n * 16 + (lane & 15);
      const size_t base = (size_t)row * NCOL + col;
#pragma unroll
      for (int r = 0; r < 4; ++r) {
        pC[base + (size_t)r * NCOL] = accC[m][n][r];
        pS[base + (size_t)r * NCOL] = accS[m][n][r];
      }
    }
  }
}

// ---- combine: radix-4 butterfly + Hermitian mirrors ----
// k in [0,256]. Direct rows d = 512*jj + k (always);
// mirror rows 2048 - d = 512*(4-jj) - k only for 1<=k<=255 (conj: outI flips).
// outR[row]=C_row, outI[row]=-S_row; mirrors: outR=C, outI=+S.
__global__ __launch_bounds__(256) void combine4_kernel(
    const float* __restrict__ pC4, const float* __restrict__ pS4,
    float* __restrict__ outR, float* __restrict__ outI) {
  const int k  = blockIdx.y;                       // 0..256
  const int jq = blockIdx.x * 256 + threadIdx.x;   // quad index
  if (jq >= NCOL / 4) return;
  const int j = jq * 4;
  const int b = j / NTP;
  const int t = j - b * NTP;                       // NTP%4==0 -> same b for all 4
  const size_t pb = (size_t)k * NCOL + j;
  f32x4 C[4], S[4];
#pragma unroll
  for (int r = 0; r < 4; ++r) {
    C[r] = *(const f32x4*)&pC4[r * PSTR + pb];
    S[r] = *(const f32x4*)&pS4[r * PSTR + pb];
  }
  const f32x4 CA = C[0] + C[2], CB = C[1] + C[3];
  const f32x4 CmA = C[0] - C[2], CmB = C[1] - C[3];
  const f32x4 SA = S[0] + S[2], SB = S[1] + S[3];
  const f32x4 SmA = S[0] - S[2], SmB = S[1] - S[3];

  f32x4 Cw[4], Sw[4];
  Cw[0] = CA + CB;   Sw[0] = SA + SB;    // row k
  Cw[1] = CmA - SmB; Sw[1] = SmA + CmB;  // row 512+k
  Cw[2] = CA - CB;   Sw[2] = SA - SB;    // row 1024+k
  Cw[3] = CmA + SmB; Sw[3] = SmA - CmB;  // row 1536+k

  const size_t ob = (size_t)b * OUTKT + t;
  const bool mir = (k >= 1) && (k <= 255);
#pragma unroll
  for (int jj = 0; jj < 4; ++jj) {
    const int rowD = 512 * jj + k;
    float* rD = outR + ob + (size_t)rowD * NT;
    float* iD = outI + ob + (size_t)rowD * NT;
    const int rowM = 512 * (4 - jj) - k;  // 2048-d: 2048-k,1536-k,1024-k,512-k
    float* rM = outR + ob + (size_t)rowM * NT;
    float* iM = outI + ob + (size_t)rowM * NT;
#pragma unroll
    for (int e = 0; e < 4; ++e) {
      if (t + e < NT) {
        rD[e] = Cw[jj][e];
        iD[e] = -Sw[jj][e];
        if (mir) { rM[e] = Cw[jj][e]; iM[e] = Sw[jj][e]; }
      }
    }
  }
}

// ==================== fallback: R4 full-K path (proven) ====================

__global__ __launch_bounds__(256) void conv_w_kernel(const float* __restrict__ wsin,
                                                     const float* __restrict__ wcos,
                                                     short* __restrict__ wc,
                                                     short* __restrict__ ws) {
  const int row = blockIdx.x;
  const int c = threadIdx.x * 8;
  const float* src = (blockIdx.y ? wsin : wcos) + (size_t)row * NFFT + c;
  short* dst = (blockIdx.y ? ws : wc) + (size_t)row * NFFT + c;
  f32x4 a = *(const f32x4*)src;
  f32x4 b = *(const f32x4*)(src + 4);
  short8 o;
#pragma unroll
  for (int j = 0; j < 4; ++j) { o[j] = cvt_bf16(a[j]); o[4 + j] = cvt_bf16(b[j]); }
  *(short8*)dst = o;
}

__global__ __launch_bounds__(256) void conv_frames_kernel(const float* __restrict__ x,
                                                          short* __restrict__ fr) {
  const int j = blockIdx.x;
  const int b = j / NTP;
  const int t = j - b * NTP;
  const int c = threadIdx.x * 8;
  short8 o;
  if (t >= NT) {
#pragma unroll
    for (int k = 0; k < 8; ++k) o[k] = 0;
  } else {
    const float* xb = x + (size_t)b * XLEN;
    const int base = t * 512 + c - 1024;
    float v[8];
    if (base >= 0 && base + 7 < XLEN) {
      *(f32x4*)(v)     = *(const f32x4*)(xb + base);
      *(f32x4*)(v + 4) = *(const f32x4*)(xb + base + 4);
    } else {
#pragma unroll
      for (int k = 0; k < 8; ++k) {
        int m = base + k;
        m = (m < 0) ? -m : m;
        m = (m >= XLEN) ? (2 * XLEN - 2 - m) : m;
        v[k] = xb[m];
      }
    }
#pragma unroll
    for (int k = 0; k < 8; ++k) o[k] = cvt_bf16(v[k]);
  }
  *(short8*)&fr[(size_t)j * NFFT + c] = o;
}

__global__ __launch_bounds__(256, 3) void dft_gemm_r4(
    const short* __restrict__ wc_bf,
    const short* __restrict__ ws_bf,
    const short* __restrict__ fr_bf,
    float* __restrict__ outR,
    float* __restrict__ outI) {
  __shared__ short lds[16384];

  const int tid  = threadIdx.x;
  const int lane = tid & 63;
  const int wid  = tid >> 6;

  const int o   = blockIdx.x;
  const int xcd = o & 7;
  const int wg  = ((xcd < 1) ? xcd * 71 : 71 + (xcd - 1) * 70) + (o >> 3);
  const int k0  = (wg % 17) * 64;
  const int j0  = (wg / 17) * 128;

  const int wrow = (wid >> 1) * 32;
  const int wcol = (wid & 1) * 64;

  f32x4 accR[2][4], accI[2][4];
#pragma unroll
  for (int m = 0; m < 2; ++m)
#pragma unroll
    for (int n = 0; n < 4; ++n) { accR[m][n] = (f32x4)0.0f; accI[m][n] = (f32x4)0.0f; }

  const int fr_r = lane & 15;
  const int srow = lane >> 3;
  const int scol = ((lane & 7) ^ srow) * 8;

  auto stage = [&](int n0) {
#pragma unroll
    for (int i = 0; i < 8; ++i) {
      const int q = wid * 8 + i;
      const short* src;
      int dst;
      if (q < 8) {
        src = wc_bf + (size_t)(k0 + q * 8 + srow) * NFFT + n0 + scol;
        dst = q * 512;
      } else if (q < 16) {
        src = ws_bf + (size_t)(k0 + (q - 8) * 8 + srow) * NFFT + n0 + scol;
        dst = 4096 + (q - 8) * 512;
      } else {
        src = fr_bf + (size_t)(j0 + (q - 16) * 8 + srow) * NFFT + n0 + scol;
        dst = 8192 + (q - 16) * 512;
      }
      gload16(src, &lds[dst]);
    }
  };

  for (int t = 0; t < 32; ++t) {
    if (t) __syncthreads();
    stage(t * 64);
    __syncthreads();
#pragma unroll
    for (int ks = 0; ks < 2; ++ks) {
      const int cc = ks * 4 + (lane >> 4);
      short8 a_c[2], a_s[2], b_f[4];
#pragma unroll
      for (int m = 0; m < 2; ++m) {
        const int r = wrow + m * 16 + fr_r;
        const int off = (r << 6) + ((cc ^ (r & 7)) << 3);
        a_c[m] = *(const short8*)&lds[off];
        a_s[m] = *(const short8*)&lds[4096 + off];
      }
#pragma unroll
      for (int n = 0; n < 4; ++n) {
        const int r = wcol + n * 16 + fr_r;
        const int off = (r << 6) + ((cc ^ (r & 7)) << 3);
        b_f[n] = *(const short8*)&lds[8192 + off];
      }
#pragma unroll
      for (int m = 0; m < 2; ++m)
#pragma unroll
        for (int n = 0; n < 4; ++n) {
          accR[m][n] = __builtin_amdgcn_mfma_f32_16x16x32_bf16(a_c[m], b_f[n], accR[m][n], 0, 0, 0);
          accI[m][n] = __builtin_amdgcn_mfma_f32_16x16x32_bf16(a_s[m], b_f[n], accI[m][n], 0, 0, 0);
        }
    }
  }

#pragma unroll
  for (int m = 0; m < 2; ++m) {
    const int k = k0 + wrow + m * 16 + (lane >> 4) * 4;
#pragma unroll
    for (int n = 0; n < 4; ++n) {
      const int j = j0 + wcol + n * 16 + (lane & 15);
      const int b = j / NTP;
      const int t = j - b * NTP;
      if (t < NT) {
        const size_t base = (size_t)b * OUTKT + (size_t)k * NT + t;
#pragma unroll
        for (int r = 0; r < 4; ++r) {
          const int kk = k + r;
          const float vr = accR[m][n][r];
          const float vi = accI[m][n][r];
          outR[base + (size_t)r * NT] = vr;
          outI[base + (size_t)r * NT] = -vi;
          if (kk >= 1 && kk <= 960) {
            const size_t mb = (size_t)b * OUTKT + (size_t)(2048 - kk) * NT + t;
            outR[mb] = vr;
            outI[mb] = vi;
          }
        }
      }
    }
  }
}

// ==================== host ====================

extern "C" void kernel_launch(void* const* d_in, const int* in_sizes, int n_in,
                              void* d_out, int out_size, void* d_ws, size_t ws_size,
                              hipStream_t stream) {
  const float* x    = (const float*)d_in[0];
  const float* wsin = (const float*)d_in[1];
  const float* wcos = (const float*)d_in[2];
  float* outR = (float*)d_out;
  float* outI = outR + (size_t)NB * OUTKT;

  // radix-4 workspace: 8 weight mats + 4 frame mats (bf16) + 8 fp32 partials
  const size_t need4 = (8 * WSTR + 4 * FSTR) * sizeof(short) + 8 * PSTR * sizeof(float);

  if (ws_size >= need4) {
    short* wc4 = (short*)d_ws;                    // [4][320][512]
    short* ws4 = wc4 + 4 * WSTR;                  // [4][320][512]
    short* fr4 = ws4 + 4 * WSTR;                  // [4][4224][512]
    float* pC4 = (float*)(fr4 + 4 * FSTR);        // [4][320][4224]
    float* pS4 = pC4 + 4 * PSTR;                  // [4][320][4224]

    conv_w_split4<<<NKC4, 256, 0, stream>>>(wsin, wcos, wc4, ws4);
    conv_fr_split4<<<NCOL, 256, 0, stream>>>(x, fr4);
    dft_gemm_split4<<<660, 256, 0, stream>>>(wc4, ws4, fr4, pC4, pS4);
    combine4_kernel<<<dim3(5, 257), 256, 0, stream>>>(pC4, pS4, outR, outI);
  } else {
    // R4 full-K fallback (needs ~26.2 MB)
    short* wc_bf = (short*)d_ws;
    short* ws_bf = wc_bf + (size_t)NK * NFFT;
    short* fr_bf = ws_bf + (size_t)NK * NFFT;
    conv_w_kernel<<<dim3(NK, 2), 256, 0, stream>>>(wsin, wcos, wc_bf, ws_bf);
    conv_frames_kernel<<<NCOL, 256, 0, stream>>>(x, fr_bf);
    dft_gemm_r4<<<561, 256, 0, stream>>>(wc_bf, ws_bf, fr_bf, outR, outI);
  }
}

// Round 14
// 61.656 us; speedup vs baseline: 1.8732x; 1.0690x over previous
//
#include <hip/hip_runtime.h>
#include <hip/hip_bf16.h>
#include <stdint.h>

#define XLEN   262144
#define NT     513
#define NTP    528               // padded frames per batch (8*528 = 4224)
#define NB     8
#define NCOL   (NB * NTP)        // 4224 fused columns
#define NKC4   320               // padded computed k rows (valid 0..256), 5 tiles
#define KQ     512               // quarter transform length (radix-4)
#define NK     1088              // fallback path: direct rows
#define NFFT   2048
#define OUTKT  (2048 * NT)
#define WSTR   ((size_t)NKC4 * KQ)   // 163,840 shorts per weight mat
#define FSTR   ((size_t)NCOL * KQ)   // 2,162,688 shorts per frame mat
#define PSTR   ((size_t)NKC4 * NCOL) // 1,351,680 elements per partial (bf16)

typedef __attribute__((ext_vector_type(8))) short short8;
typedef __attribute__((ext_vector_type(4))) short short4v;
typedef __attribute__((ext_vector_type(2))) short short2v;
typedef __attribute__((ext_vector_type(4))) float f32x4;

__device__ __forceinline__ short cvt_bf16(float f) {
  return __builtin_bit_cast(short, (__bf16)f);
}

__device__ __forceinline__ f32x4 bf4_to_f32(short4v v) {
  f32x4 o;
#pragma unroll
  for (int e = 0; e < 4; ++e) {
    uint32_t u = ((uint32_t)(uint16_t)v[e]) << 16;
    o[e] = __builtin_bit_cast(float, u);
  }
  return o;
}

__device__ __forceinline__ void gload16(const short* g, const short* l) {
  __builtin_amdgcn_global_load_lds(
      (const __attribute__((address_space(1))) void*)g,
      (__attribute__((address_space(3))) void*)l, 16, 0, 0);
}

// ==================== radix-4 split path ====================

// ---- prep: weights rows 0..256 split by n mod 4 -> 8 bf16 mats [320][512] ----
__global__ __launch_bounds__(256) void conv_w_split4(
    const float* __restrict__ wsin, const float* __restrict__ wcos,
    short* __restrict__ wc4, short* __restrict__ ws4) {
  const int row = blockIdx.x;           // 0..319
  const int n0 = threadIdx.x * 8;       // 8 consecutive n; m0 = n0/4 (even)
  const int m0 = n0 >> 2;
  short2v c[4], s[4];
  if (row <= 256) {
    const float* pc = wcos + (size_t)row * NFFT + n0;
    const float* ps = wsin + (size_t)row * NFFT + n0;
    f32x4 c0 = *(const f32x4*)pc, c1 = *(const f32x4*)(pc + 4);
    f32x4 s0 = *(const f32x4*)ps, s1 = *(const f32x4*)(ps + 4);
#pragma unroll
    for (int r = 0; r < 4; ++r) {
      c[r][0] = cvt_bf16(c0[r]); c[r][1] = cvt_bf16(c1[r]);
      s[r][0] = cvt_bf16(s0[r]); s[r][1] = cvt_bf16(s1[r]);
    }
  } else {
#pragma unroll
    for (int r = 0; r < 4; ++r) { c[r][0] = 0; c[r][1] = 0; s[r][0] = 0; s[r][1] = 0; }
  }
#pragma unroll
  for (int r = 0; r < 4; ++r) {
    *(short2v*)&wc4[r * WSTR + (size_t)row * KQ + m0] = c[r];
    *(short2v*)&ws4[r * WSTR + (size_t)row * KQ + m0] = s[r];
  }
}

// ---- prep: reflect-padded frames split by n mod 4 -> 4 bf16 mats [4224][512] ----
__global__ __launch_bounds__(256) void conv_fr_split4(const float* __restrict__ x,
                                                      short* __restrict__ fr4) {
  const int j = blockIdx.x;
  const int b = j / NTP;
  const int t = j - b * NTP;
  const int n0 = threadIdx.x * 8;
  const int m0 = n0 >> 2;
  short2v v[4];
  if (t < NT) {
    const float* xb = x + (size_t)b * XLEN;
    const int q0 = t * 512 + n0 - 1024;
    float f[8];
    if (q0 >= 0 && q0 + 7 < XLEN) {
      *(f32x4*)(f)     = *(const f32x4*)(xb + q0);
      *(f32x4*)(f + 4) = *(const f32x4*)(xb + q0 + 4);
    } else {
#pragma unroll
      for (int e = 0; e < 8; ++e) {
        int mm = q0 + e;
        mm = (mm < 0) ? -mm : mm;
        mm = (mm >= XLEN) ? (2 * XLEN - 2 - mm) : mm;
        f[e] = xb[mm];
      }
    }
#pragma unroll
    for (int r = 0; r < 4; ++r) { v[r][0] = cvt_bf16(f[r]); v[r][1] = cvt_bf16(f[4 + r]); }
  } else {
#pragma unroll
    for (int r = 0; r < 4; ++r) { v[r][0] = 0; v[r][1] = 0; }
  }
#pragma unroll
  for (int r = 0; r < 4; ++r)
    *(short2v*)&fr4[r * FSTR + (size_t)j * KQ + m0] = v[r];
}

// ---- split GEMM: R11-proven structure, K=512, one residue side per block ----
// BM=64, BN=128, BK=64; 4 waves 2x2, each 32x64 per matrix; per substep
// 8 ds_read_b128 : 16 MFMA. LDS single 32 KiB [A_c 64x64 | A_s 64x64 | B 128x64],
// (row&7) 16B-chunk XOR swizzle on global source + ds_read (rule #21).
// Partials written as bf16 (halves partial traffic; error budget audited).
__global__ __launch_bounds__(256, 3) void dft_gemm_split4(
    const short* __restrict__ wc4, const short* __restrict__ ws4,
    const short* __restrict__ fr4,
    short* __restrict__ pC4, short* __restrict__ pS4) {
  __shared__ short lds[16384];  // 32 KiB

  const int tid  = threadIdx.x;
  const int lane = tid & 63;
  const int wid  = tid >> 6;

  // bijective XCD swizzle (m204): nwg=660, q=82, r=4.
  const int o   = blockIdx.x;
  const int xcd = o & 7;
  const int i   = o >> 3;
  const int wg  = ((xcd < 4) ? xcd * 83 : 332 + (xcd - 4) * 82) + i;
  const int side = wg / 165;        // residue r = 0..3
  const int w    = wg - side * 165;
  const int k0   = (w % 5) * 64;
  const int j0   = (w / 5) * 128;

  const short* Ac = wc4 + side * WSTR;
  const short* As = ws4 + side * WSTR;
  const short* Bf = fr4 + side * FSTR;
  short* pC = pC4 + side * PSTR;
  short* pS = pS4 + side * PSTR;

  const int wrow = (wid >> 1) * 32;
  const int wcol = (wid & 1) * 64;

  f32x4 accC[2][4], accS[2][4];
#pragma unroll
  for (int m = 0; m < 2; ++m)
#pragma unroll
    for (int n = 0; n < 4; ++n) { accC[m][n] = (f32x4)0.0f; accS[m][n] = (f32x4)0.0f; }

  const int fr_r = lane & 15;
  const int srow = lane >> 3;
  const int scol = ((lane & 7) ^ srow) * 8;

  // buffer = 32 chunks of (8 rows x 64 shorts); 8 per wave
  auto stage = [&](int n0) {
#pragma unroll
    for (int i2 = 0; i2 < 8; ++i2) {
      const int q = wid * 8 + i2;  // wave-uniform
      const short* src;
      int dst;
      if (q < 8) {
        src = Ac + (size_t)(k0 + q * 8 + srow) * KQ + n0 + scol;
        dst = q * 512;
      } else if (q < 16) {
        src = As + (size_t)(k0 + (q - 8) * 8 + srow) * KQ + n0 + scol;
        dst = 4096 + (q - 8) * 512;
      } else {
        src = Bf + (size_t)(j0 + (q - 16) * 8 + srow) * KQ + n0 + scol;
        dst = 8192 + (q - 16) * 512;
      }
      gload16(src, &lds[dst]);
    }
  };

  for (int ts = 0; ts < 8; ++ts) {
    if (ts) __syncthreads();
    stage(ts * 64);
    __syncthreads();
#pragma unroll
    for (int ks = 0; ks < 2; ++ks) {
      const int cc = ks * 4 + (lane >> 4);
      short8 aC[2], aS[2], bF[4];
#pragma unroll
      for (int m = 0; m < 2; ++m) {
        const int r = wrow + m * 16 + fr_r;
        const int off = (r << 6) + ((cc ^ (r & 7)) << 3);
        aC[m] = *(const short8*)&lds[off];
        aS[m] = *(const short8*)&lds[4096 + off];
      }
#pragma unroll
      for (int n = 0; n < 4; ++n) {
        const int r = wcol + n * 16 + fr_r;
        const int off = (r << 6) + ((cc ^ (r & 7)) << 3);
        bF[n] = *(const short8*)&lds[8192 + off];
      }
#pragma unroll
      for (int m = 0; m < 2; ++m)
#pragma unroll
        for (int n = 0; n < 4; ++n) {
          accC[m][n] = __builtin_amdgcn_mfma_f32_16x16x32_bf16(aC[m], bF[n], accC[m][n], 0, 0, 0);
          accS[m][n] = __builtin_amdgcn_mfma_f32_16x16x32_bf16(aS[m], bF[n], accS[m][n], 0, 0, 0);
        }
    }
  }

  // epilogue: bf16 partial write (16 consecutive lanes -> 32B contiguous)
#pragma unroll
  for (int m = 0; m < 2; ++m) {
    const int row = k0 + wrow + m * 16 + (lane >> 4) * 4;
#pragma unroll
    for (int n = 0; n < 4; ++n) {
      const int col = j0 + wcol + n * 16 + (lane & 15);
      const size_t base = (size_t)row * NCOL + col;
#pragma unroll
      for (int r = 0; r < 4; ++r) {
        pC[base + (size_t)r * NCOL] = cvt_bf16(accC[m][n][r]);
        pS[base + (size_t)r * NCOL] = cvt_bf16(accS[m][n][r]);
      }
    }
  }
}

// ---- combine: radix-4 butterfly + Hermitian mirrors (bf16 partials in) ----
// k in [0,256]. Direct rows d = 512*jj + k (always);
// mirror rows 2048 - d = 512*(4-jj) - k only for 1<=k<=255 (conj: outI flips).
// outR[row]=C_row, outI[row]=-S_row; mirrors: outR=C, outI=+S.
__global__ __launch_bounds__(256) void combine4_kernel(
    const short* __restrict__ pC4, const short* __restrict__ pS4,
    float* __restrict__ outR, float* __restrict__ outI) {
  const int k  = blockIdx.y;                       // 0..256
  const int jq = blockIdx.x * 256 + threadIdx.x;   // quad index
  if (jq >= NCOL / 4) return;
  const int j = jq * 4;
  const int b = j / NTP;
  const int t = j - b * NTP;                       // NTP%4==0 -> same b for all 4
  const size_t pb = (size_t)k * NCOL + j;
  f32x4 C[4], S[4];
#pragma unroll
  for (int r = 0; r < 4; ++r) {
    C[r] = bf4_to_f32(*(const short4v*)&pC4[r * PSTR + pb]);
    S[r] = bf4_to_f32(*(const short4v*)&pS4[r * PSTR + pb]);
  }
  const f32x4 CA = C[0] + C[2], CB = C[1] + C[3];
  const f32x4 CmA = C[0] - C[2], CmB = C[1] - C[3];
  const f32x4 SA = S[0] + S[2], SB = S[1] + S[3];
  const f32x4 SmA = S[0] - S[2], SmB = S[1] - S[3];

  f32x4 Cw[4], Sw[4];
  Cw[0] = CA + CB;   Sw[0] = SA + SB;    // row k
  Cw[1] = CmA - SmB; Sw[1] = SmA + CmB;  // row 512+k
  Cw[2] = CA - CB;   Sw[2] = SA - SB;    // row 1024+k
  Cw[3] = CmA + SmB; Sw[3] = SmA - CmB;  // row 1536+k

  const size_t ob = (size_t)b * OUTKT + t;
  const bool mir = (k >= 1) && (k <= 255);
#pragma unroll
  for (int jj = 0; jj < 4; ++jj) {
    const int rowD = 512 * jj + k;
    float* rD = outR + ob + (size_t)rowD * NT;
    float* iD = outI + ob + (size_t)rowD * NT;
    const int rowM = 512 * (4 - jj) - k;  // 2048-d: 2048-k,1536-k,1024-k,512-k
    float* rM = outR + ob + (size_t)rowM * NT;
    float* iM = outI + ob + (size_t)rowM * NT;
#pragma unroll
    for (int e = 0; e < 4; ++e) {
      if (t + e < NT) {
        rD[e] = Cw[jj][e];
        iD[e] = -Sw[jj][e];
        if (mir) { rM[e] = Cw[jj][e]; iM[e] = Sw[jj][e]; }
      }
    }
  }
}

// ==================== fallback: R4 full-K path (proven) ====================

__global__ __launch_bounds__(256) void conv_w_kernel(const float* __restrict__ wsin,
                                                     const float* __restrict__ wcos,
                                                     short* __restrict__ wc,
                                                     short* __restrict__ ws) {
  const int row = blockIdx.x;
  const int c = threadIdx.x * 8;
  const float* src = (blockIdx.y ? wsin : wcos) + (size_t)row * NFFT + c;
  short* dst = (blockIdx.y ? ws : wc) + (size_t)row * NFFT + c;
  f32x4 a = *(const f32x4*)src;
  f32x4 b = *(const f32x4*)(src + 4);
  short8 o;
#pragma unroll
  for (int j = 0; j < 4; ++j) { o[j] = cvt_bf16(a[j]); o[4 + j] = cvt_bf16(b[j]); }
  *(short8*)dst = o;
}

__global__ __launch_bounds__(256) void conv_frames_kernel(const float* __restrict__ x,
                                                          short* __restrict__ fr) {
  const int j = blockIdx.x;
  const int b = j / NTP;
  const int t = j - b * NTP;
  const int c = threadIdx.x * 8;
  short8 o;
  if (t >= NT) {
#pragma unroll
    for (int k = 0; k < 8; ++k) o[k] = 0;
  } else {
    const float* xb = x + (size_t)b * XLEN;
    const int base = t * 512 + c - 1024;
    float v[8];
    if (base >= 0 && base + 7 < XLEN) {
      *(f32x4*)(v)     = *(const f32x4*)(xb + base);
      *(f32x4*)(v + 4) = *(const f32x4*)(xb + base + 4);
    } else {
#pragma unroll
      for (int k = 0; k < 8; ++k) {
        int m = base + k;
        m = (m < 0) ? -m : m;
        m = (m >= XLEN) ? (2 * XLEN - 2 - m) : m;
        v[k] = xb[m];
      }
    }
#pragma unroll
    for (int k = 0; k < 8; ++k) o[k] = cvt_bf16(v[k]);
  }
  *(short8*)&fr[(size_t)j * NFFT + c] = o;
}

__global__ __launch_bounds__(256, 3) void dft_gemm_r4(
    const short* __restrict__ wc_bf,
    const short* __restrict__ ws_bf,
    const short* __restrict__ fr_bf,
    float* __restrict__ outR,
    float* __restrict__ outI) {
  __shared__ short lds[16384];

  const int tid  = threadIdx.x;
  const int lane = tid & 63;
  const int wid  = tid >> 6;

  const int o   = blockIdx.x;
  const int xcd = o & 7;
  const int wg  = ((xcd < 1) ? xcd * 71 : 71 + (xcd - 1) * 70) + (o >> 3);
  const int k0  = (wg % 17) * 64;
  const int j0  = (wg / 17) * 128;

  const int wrow = (wid >> 1) * 32;
  const int wcol = (wid & 1) * 64;

  f32x4 accR[2][4], accI[2][4];
#pragma unroll
  for (int m = 0; m < 2; ++m)
#pragma unroll
    for (int n = 0; n < 4; ++n) { accR[m][n] = (f32x4)0.0f; accI[m][n] = (f32x4)0.0f; }

  const int fr_r = lane & 15;
  const int srow = lane >> 3;
  const int scol = ((lane & 7) ^ srow) * 8;

  auto stage = [&](int n0) {
#pragma unroll
    for (int i = 0; i < 8; ++i) {
      const int q = wid * 8 + i;
      const short* src;
      int dst;
      if (q < 8) {
        src = wc_bf + (size_t)(k0 + q * 8 + srow) * NFFT + n0 + scol;
        dst = q * 512;
      } else if (q < 16) {
        src = ws_bf + (size_t)(k0 + (q - 8) * 8 + srow) * NFFT + n0 + scol;
        dst = 4096 + (q - 8) * 512;
      } else {
        src = fr_bf + (size_t)(j0 + (q - 16) * 8 + srow) * NFFT + n0 + scol;
        dst = 8192 + (q - 16) * 512;
      }
      gload16(src, &lds[dst]);
    }
  };

  for (int t = 0; t < 32; ++t) {
    if (t) __syncthreads();
    stage(t * 64);
    __syncthreads();
#pragma unroll
    for (int ks = 0; ks < 2; ++ks) {
      const int cc = ks * 4 + (lane >> 4);
      short8 a_c[2], a_s[2], b_f[4];
#pragma unroll
      for (int m = 0; m < 2; ++m) {
        const int r = wrow + m * 16 + fr_r;
        const int off = (r << 6) + ((cc ^ (r & 7)) << 3);
        a_c[m] = *(const short8*)&lds[off];
        a_s[m] = *(const short8*)&lds[4096 + off];
      }
#pragma unroll
      for (int n = 0; n < 4; ++n) {
        const int r = wcol + n * 16 + fr_r;
        const int off = (r << 6) + ((cc ^ (r & 7)) << 3);
        b_f[n] = *(const short8*)&lds[8192 + off];
      }
#pragma unroll
      for (int m = 0; m < 2; ++m)
#pragma unroll
        for (int n = 0; n < 4; ++n) {
          accR[m][n] = __builtin_amdgcn_mfma_f32_16x16x32_bf16(a_c[m], b_f[n], accR[m][n], 0, 0, 0);
          accI[m][n] = __builtin_amdgcn_mfma_f32_16x16x32_bf16(a_s[m], b_f[n], accI[m][n], 0, 0, 0);
        }
    }
  }

#pragma unroll
  for (int m = 0; m < 2; ++m) {
    const int k = k0 + wrow + m * 16 + (lane >> 4) * 4;
#pragma unroll
    for (int n = 0; n < 4; ++n) {
      const int j = j0 + wcol + n * 16 + (lane & 15);
      const int b = j / NTP;
      const int t = j - b * NTP;
      if (t < NT) {
        const size_t base = (size_t)b * OUTKT + (size_t)k * NT + t;
#pragma unroll
        for (int r = 0; r < 4; ++r) {
          const int kk = k + r;
          const float vr = accR[m][n][r];
          const float vi = accI[m][n][r];
          outR[base + (size_t)r * NT] = vr;
          outI[base + (size_t)r * NT] = -vi;
          if (kk >= 1 && kk <= 960) {
            const size_t mb = (size_t)b * OUTKT + (size_t)(2048 - kk) * NT + t;
            outR[mb] = vr;
            outI[mb] = vi;
          }
        }
      }
    }
  }
}

// ==================== host ====================

extern "C" void kernel_launch(void* const* d_in, const int* in_sizes, int n_in,
                              void* d_out, int out_size, void* d_ws, size_t ws_size,
                              hipStream_t stream) {
  const float* x    = (const float*)d_in[0];
  const float* wsin = (const float*)d_in[1];
  const float* wcos = (const float*)d_in[2];
  float* outR = (float*)d_out;
  float* outI = outR + (size_t)NB * OUTKT;

  // radix-4 workspace: 8 weight mats + 4 frame mats + 8 bf16 partials
  const size_t need4 = (8 * WSTR + 4 * FSTR + 8 * PSTR) * sizeof(short);

  if (ws_size >= need4) {
    short* wc4 = (short*)d_ws;                    // [4][320][512]
    short* ws4 = wc4 + 4 * WSTR;                  // [4][320][512]
    short* fr4 = ws4 + 4 * WSTR;                  // [4][4224][512]
    short* pC4 = fr4 + 4 * FSTR;                  // [4][320][4224] bf16
    short* pS4 = pC4 + 4 * PSTR;                  // [4][320][4224] bf16

    conv_w_split4<<<NKC4, 256, 0, stream>>>(wsin, wcos, wc4, ws4);
    conv_fr_split4<<<NCOL, 256, 0, stream>>>(x, fr4);
    dft_gemm_split4<<<660, 256, 0, stream>>>(wc4, ws4, fr4, pC4, pS4);
    combine4_kernel<<<dim3(5, 257), 256, 0, stream>>>(pC4, pS4, outR, outI);
  } else {
    // R4 full-K fallback (needs ~26.2 MB)
    short* wc_bf = (short*)d_ws;
    short* ws_bf = wc_bf + (size_t)NK * NFFT;
    short* fr_bf = ws_bf + (size_t)NK * NFFT;
    conv_w_kernel<<<dim3(NK, 2), 256, 0, stream>>>(wsin, wcos, wc_bf, ws_bf);
    conv_frames_kernel<<<NCOL, 256, 0, stream>>>(x, fr_bf);
    dft_gemm_r4<<<561, 256, 0, stream>>>(wc_bf, ws_bf, fr_bf, outR, outI);
  }
}